// Round 1
// baseline (1424.678 us; speedup 1.0000x reference)
//
#include <hip/hip_runtime.h>
#include <hip/hip_bf16.h>
#include <cstdint>
#include <cstddef>

#define TILE 128
#define BK 32
#define NTHREADS 256

typedef __attribute__((ext_vector_type(8))) short bf16x8;
typedef __attribute__((ext_vector_type(4))) float f32x4;
typedef __attribute__((ext_vector_type(4))) uint16_t u16x4;
typedef __attribute__((ext_vector_type(8))) uint16_t u16x8;

#define GLOBAL_AS __attribute__((address_space(1)))
#define LDS_AS __attribute__((address_space(3)))

__device__ inline uint16_t f2b(float f) {
    // round-to-nearest-even fp32 -> bf16 (inputs are finite; no NaN handling needed)
    uint32_t x = __float_as_uint(f);
    uint32_t r = (x + 0x7fffu + ((x >> 16) & 1u)) >> 16;
    return (uint16_t)r;
}

// ---------------------------------------------------------------- convert
__global__ void cvt_kernel(const float* __restrict__ in, uint16_t* __restrict__ out,
                           size_t n8) {
    size_t stride = (size_t)gridDim.x * blockDim.x;
    for (size_t i = (size_t)blockIdx.x * blockDim.x + threadIdx.x; i < n8; i += stride) {
        const float4* p = (const float4*)(in + i * 8);
        float4 a = p[0], b = p[1];
        u16x8 o;
        o[0] = f2b(a.x); o[1] = f2b(a.y); o[2] = f2b(a.z); o[3] = f2b(a.w);
        o[4] = f2b(b.x); o[5] = f2b(b.y); o[6] = f2b(b.z); o[7] = f2b(b.w);
        *(u16x8*)(out + i * 8) = o;
    }
}

// ---------------------------------------------------------------- fused GEMM + partial LSE
// Computes logits tile [128 rows x 128 vocab cols] via bf16 MFMA, then per-row
// (max, sumexp) partials and the target logit. Never materializes full logits.
template <bool B16WS>
__global__ void flce_gemm(const void* __restrict__ Aptr, const void* __restrict__ Bptr,
                          const long long* __restrict__ target,
                          float2* __restrict__ partials, float* __restrict__ tgt_logit,
                          int BT, int H, int V, int nrb) {
    __shared__ uint16_t As[TILE * BK];   // [128][32] bf16, linear
    __shared__ uint16_t Bs[TILE * BK];
    __shared__ float red_m[TILE][2];
    __shared__ float red_s[TILE][2];
    __shared__ int tgt_l[TILE];

    const int tid  = threadIdx.x;
    const int wave = tid >> 6, lane = tid & 63;
    const int wr = wave >> 1, wc = wave & 1;       // 2x2 wave grid, each wave 64x64
    const int l16 = lane & 15, lh = lane >> 4;

    const int bid = blockIdx.x;
    const int rb = bid % nrb, cb = bid / nrb;      // consecutive blocks share W panel
    const int brow = rb * TILE, bcol = cb * TILE;

    if (tid < TILE) {
        long long t = target[brow + tid];
        if (t < 0) t = 0;
        if (t >= V) t = (long long)V - 1;
        tgt_l[tid] = (int)t;
    }

    f32x4 acc[4][4] = {};

    for (int k0 = 0; k0 < H; k0 += BK) {
        __syncthreads();  // all waves done reading LDS from previous iteration
        if constexpr (B16WS) {
            const uint16_t* X  = (const uint16_t*)Aptr;
            const uint16_t* Wb = (const uint16_t*)Bptr;
#pragma unroll
            for (int c = 0; c < 2; ++c) {
                int ci  = wave * 2 + c;                 // 16-row chunk (1024 B)
                int row = ci * 16 + (lane >> 2);        // lane l -> row + k-slot
                const uint16_t* ga = X  + (size_t)(brow + row) * H + k0 + (lane & 3) * 8;
                const uint16_t* gb = Wb + (size_t)(bcol + row) * H + k0 + (lane & 3) * 8;
                __builtin_amdgcn_global_load_lds((const GLOBAL_AS uint32_t*)ga,
                                                 (LDS_AS uint32_t*)&As[ci * 512], 16, 0, 0);
                __builtin_amdgcn_global_load_lds((const GLOBAL_AS uint32_t*)gb,
                                                 (LDS_AS uint32_t*)&Bs[ci * 512], 16, 0, 0);
            }
        } else {
            const float* X  = (const float*)Aptr;
            const float* Wf = (const float*)Bptr;
#pragma unroll
            for (int j = 0; j < 4; ++j) {
                int fi  = tid + j * NTHREADS;           // float4 index within 128x32 tile
                int row = fi >> 3;                      // 8 float4 per row
                int kk  = (fi & 7) << 2;
                float4 av = *(const float4*)(X  + (size_t)(brow + row) * H + k0 + kk);
                float4 bv = *(const float4*)(Wf + (size_t)(bcol + row) * H + k0 + kk);
                u16x4 au, bu;
                au[0] = f2b(av.x); au[1] = f2b(av.y); au[2] = f2b(av.z); au[3] = f2b(av.w);
                bu[0] = f2b(bv.x); bu[1] = f2b(bv.y); bu[2] = f2b(bv.z); bu[3] = f2b(bv.w);
                *(u16x4*)&As[row * BK + kk] = au;
                *(u16x4*)&Bs[row * BK + kk] = bu;
            }
        }
        __syncthreads();  // implicit vmcnt(0)/lgkmcnt(0) drain -> tiles ready

        bf16x8 af[4], bf[4];
#pragma unroll
        for (int m = 0; m < 4; ++m)
            af[m] = *(const bf16x8*)&As[(wr * 64 + m * 16 + l16) * BK + lh * 8];
#pragma unroll
        for (int n = 0; n < 4; ++n)
            bf[n] = *(const bf16x8*)&Bs[(wc * 64 + n * 16 + l16) * BK + lh * 8];
#pragma unroll
        for (int m = 0; m < 4; ++m)
#pragma unroll
            for (int n = 0; n < 4; ++n)
                acc[m][n] = __builtin_amdgcn_mfma_f32_16x16x32_bf16(af[m], bf[n],
                                                                    acc[m][n], 0, 0, 0);
    }

    // ---- epilogue: per-row max / sumexp over this tile's 128 cols + target pick
    // C/D layout: col = lane&15, row = (lane>>4)*4 + reg  [measured m89/m91]
#pragma unroll
    for (int m = 0; m < 4; ++m) {
#pragma unroll
        for (int r = 0; r < 4; ++r) {
            int rowl = wr * 64 + m * 16 + lh * 4 + r;   // row within block tile
            int tc = tgt_l[rowl] - bcol;                 // target col within tile (may be OOR)
            float mx = -INFINITY;
#pragma unroll
            for (int n = 0; n < 4; ++n) {
                float v = acc[m][n][r];
                if (tc == wc * 64 + n * 16 + l16) tgt_logit[brow + rowl] = v;
                mx = fmaxf(mx, v);
            }
#pragma unroll
            for (int d = 1; d < 16; d <<= 1) mx = fmaxf(mx, __shfl_xor(mx, d));
            float s = 0.f;
#pragma unroll
            for (int n = 0; n < 4; ++n) s += __expf(acc[m][n][r] - mx);
#pragma unroll
            for (int d = 1; d < 16; d <<= 1) s += __shfl_xor(s, d);
            if (l16 == 0) { red_m[rowl][wc] = mx; red_s[rowl][wc] = s; }
        }
    }
    __syncthreads();
    if (tid < TILE) {
        float m0 = red_m[tid][0], m1 = red_m[tid][1];
        float s0 = red_s[tid][0], s1 = red_s[tid][1];
        float M = fmaxf(m0, m1);
        float S = s0 * __expf(m0 - M) + s1 * __expf(m1 - M);
        partials[(size_t)cb * BT + brow + tid] = make_float2(M, S);
    }
}

// ---------------------------------------------------------------- per-row LSE merge + block sums
__global__ void flce_reduce(const float2* __restrict__ partials,
                            const float* __restrict__ tgt_logit,
                            const long long* __restrict__ target,
                            float2* __restrict__ bsums, int BT, int NCB) {
    int row = blockIdx.x * blockDim.x + threadIdx.x;
    float M = -INFINITY, S = 0.f;
    for (int cb = 0; cb < NCB; ++cb) {
        float2 p = partials[(size_t)cb * BT + row];
        float Mn = fmaxf(M, p.x);
        S = S * __expf(M - Mn) + p.y * __expf(p.x - Mn);
        M = Mn;
    }
    float lse = M + __logf(S);
    bool valid = (target[row] != -100);
    float nll = valid ? (lse - tgt_logit[row]) : 0.f;
    float cnt = valid ? 1.f : 0.f;
#pragma unroll
    for (int d = 1; d < 64; d <<= 1) { nll += __shfl_xor(nll, d); cnt += __shfl_xor(cnt, d); }
    __shared__ float sm[8][2];
    int w = threadIdx.x >> 6;
    if ((threadIdx.x & 63) == 0) { sm[w][0] = nll; sm[w][1] = cnt; }
    __syncthreads();
    if (threadIdx.x == 0) {
        float sn = 0.f, sc = 0.f;
        int nw = blockDim.x >> 6;
        for (int i = 0; i < nw; ++i) { sn += sm[i][0]; sc += sm[i][1]; }
        bsums[blockIdx.x] = make_float2(sn, sc);
    }
}

__global__ void flce_final(const float2* __restrict__ bsums, int nb, float* __restrict__ out) {
    if (blockIdx.x == 0 && threadIdx.x == 0) {
        float sn = 0.f, sc = 0.f;
        for (int i = 0; i < nb; ++i) { sn += bsums[i].x; sc += bsums[i].y; }
        out[0] = sn / sc;
    }
}

// ---------------------------------------------------------------- launch
extern "C" void kernel_launch(void* const* d_in, const int* in_sizes, int n_in,
                              void* d_out, int out_size, void* d_ws, size_t ws_size,
                              hipStream_t stream) {
    const float* x = (const float*)d_in[0];
    const float* w = (const float*)d_in[1];
    const long long* target = (const long long*)d_in[2];
    float* out = (float*)d_out;

    const int BT = in_sizes[2];
    const int H  = in_sizes[0] / BT;
    const int V  = in_sizes[1] / H;
    const int nrb = BT / TILE;      // 32
    const int ncb = V / TILE;       // 250
    const int nred = BT / 256;      // 16 reduce blocks

    char* ws = (char*)d_ws;
    size_t szW    = (size_t)V * H * sizeof(uint16_t);
    size_t szX    = (size_t)BT * H * sizeof(uint16_t);
    size_t szPart = (size_t)ncb * BT * sizeof(float2);
    size_t szTgt  = (size_t)BT * sizeof(float);
    size_t szB    = (size_t)nred * sizeof(float2);

    bool use16 = ws_size >= szW + szX + szPart + szTgt + szB;

    float2* partials;
    float*  tgtlog;
    float2* bsums;

    if (use16) {
        uint16_t* Wb = (uint16_t*)ws;
        uint16_t* Xb = (uint16_t*)(ws + szW);
        partials = (float2*)(ws + szW + szX);
        tgtlog   = (float*)(ws + szW + szX + szPart);
        bsums    = (float2*)(ws + szW + szX + szPart + szTgt);

        hipLaunchKernelGGL(cvt_kernel, dim3(1024), dim3(256), 0, stream,
                           x, Xb, (size_t)BT * H / 8);
        hipLaunchKernelGGL(cvt_kernel, dim3(4096), dim3(256), 0, stream,
                           w, Wb, (size_t)V * H / 8);
        hipLaunchKernelGGL((flce_gemm<true>), dim3(nrb * ncb), dim3(NTHREADS), 0, stream,
                           (const void*)Xb, (const void*)Wb, target,
                           partials, tgtlog, BT, H, V, nrb);
    } else {
        partials = (float2*)ws;
        tgtlog   = (float*)(ws + szPart);
        bsums    = (float2*)(ws + szPart + szTgt);
        hipLaunchKernelGGL((flce_gemm<false>), dim3(nrb * ncb), dim3(NTHREADS), 0, stream,
                           (const void*)x, (const void*)w, target,
                           partials, tgtlog, BT, H, V, nrb);
    }

    hipLaunchKernelGGL(flce_reduce, dim3(BT / 256), dim3(256), 0, stream,
                       partials, tgtlog, target, bsums, BT, ncb);
    hipLaunchKernelGGL(flce_final, dim3(1), dim3(64), 0, stream, bsums, nred, out);
}

// Round 2
// 1157.249 us; speedup vs baseline: 1.2311x; 1.2311x over previous
//
#include <hip/hip_runtime.h>
#include <hip/hip_bf16.h>
#include <cstdint>
#include <cstddef>

typedef __attribute__((ext_vector_type(8))) short bf16x8;
typedef __attribute__((ext_vector_type(4))) float f32x4;
typedef __attribute__((ext_vector_type(4))) uint16_t u16x4;
typedef __attribute__((ext_vector_type(8))) uint16_t u16x8;

#define GLOBAL_AS __attribute__((address_space(1)))
#define LDS_AS __attribute__((address_space(3)))

__device__ inline uint16_t f2b(float f) {
    uint32_t x = __float_as_uint(f);
    uint32_t r = (x + 0x7fffu + ((x >> 16) & 1u)) >> 16;
    return (uint16_t)r;
}

// ---------------------------------------------------------------- convert fp32 -> bf16
__global__ void cvt_kernel(const float* __restrict__ in, uint16_t* __restrict__ out,
                           size_t n8) {
    size_t stride = (size_t)gridDim.x * blockDim.x;
    for (size_t i = (size_t)blockIdx.x * blockDim.x + threadIdx.x; i < n8; i += stride) {
        const float4* p = (const float4*)(in + i * 8);
        float4 a = p[0], b = p[1];
        u16x8 o;
        o[0] = f2b(a.x); o[1] = f2b(a.y); o[2] = f2b(a.z); o[3] = f2b(a.w);
        o[4] = f2b(b.x); o[5] = f2b(b.y); o[6] = f2b(b.z); o[7] = f2b(b.w);
        *(u16x8*)(out + i * 8) = o;
    }
}

// ---------------------------------------------------------------- 8-phase 256x256 fused GEMM+LSE
// T2 read-side swizzle: linear byte offset o (128B rows) -> o ^ ((row&7)<<4).
// Staged via inverse-permuted global source + linear global_load_lds dest.

__device__ __forceinline__ void stage_half(const uint16_t* g0, const uint16_t* g1,
                                           uint16_t* region, int chunk0) {
    __builtin_amdgcn_global_load_lds((const GLOBAL_AS uint32_t*)g0,
                                     (LDS_AS uint32_t*)(region + chunk0 * 512), 16, 0, 0);
    __builtin_amdgcn_global_load_lds((const GLOBAL_AS uint32_t*)g1,
                                     (LDS_AS uint32_t*)(region + (chunk0 + 1) * 512), 16, 0, 0);
}

__device__ __forceinline__ void load_a(bf16x8 a[4][2], const uint16_t* region,
                                       int wr, int l16, int lh) {
    const int xorv = (l16 & 7) << 4;
#pragma unroll
    for (int mi = 0; mi < 4; ++mi) {
        const char* rowp = (const char*)region + (wr * 64 + mi * 16 + l16) * 128;
#pragma unroll
        for (int kk = 0; kk < 2; ++kk)
            a[mi][kk] = *(const bf16x8*)(rowp + ((kk * 64 + lh * 16) ^ xorv));
    }
}

__device__ __forceinline__ void load_b(bf16x8 b[2][2], const uint16_t* region,
                                       int wc, int l16, int lh) {
    const int xorv = (l16 & 7) << 4;
#pragma unroll
    for (int ni = 0; ni < 2; ++ni) {
        const char* rowp = (const char*)region + (wc * 32 + ni * 16 + l16) * 128;
#pragma unroll
        for (int kk = 0; kk < 2; ++kk)
            b[ni][kk] = *(const bf16x8*)(rowp + ((kk * 64 + lh * 16) ^ xorv));
    }
}

template <int MH, int NH>
__device__ __forceinline__ void mfma_quad(f32x4 acc[2][2][4][2], const bf16x8 a[4][2],
                                          const bf16x8 b[2][2][2]) {
    __builtin_amdgcn_s_setprio(1);
#pragma unroll
    for (int mi = 0; mi < 4; ++mi)
#pragma unroll
        for (int ni = 0; ni < 2; ++ni)
#pragma unroll
            for (int kk = 0; kk < 2; ++kk)
                acc[MH][NH][mi][ni] = __builtin_amdgcn_mfma_f32_16x16x32_bf16(
                    a[mi][kk], b[NH][ni][kk], acc[MH][NH][mi][ni], 0, 0, 0);
    __builtin_amdgcn_s_setprio(0);
}

__device__ __forceinline__ void phase_sync() {
    __builtin_amdgcn_s_barrier();
    asm volatile("s_waitcnt lgkmcnt(0)" ::: "memory");
}

__global__ __launch_bounds__(512, 2)
void flce_gemm8(const uint16_t* __restrict__ Xb, const uint16_t* __restrict__ Wb,
                const long long* __restrict__ target,
                float2* __restrict__ partials, float* __restrict__ tgt_logit,
                int BT, int H, int V, int nrb) {
    __shared__ __align__(16) char smem[131072];   // A: 4 regions x 16KB, B: same
    uint16_t* Ab = (uint16_t*)smem;
    uint16_t* Bb = (uint16_t*)(smem + 65536);
#define ALDS(bf, hf) (Ab + ((bf) * 2 + (hf)) * 8192)
#define BLDS(bf, hf) (Bb + ((bf) * 2 + (hf)) * 8192)

    const int tid = threadIdx.x;
    const int lane = tid & 63, wave = tid >> 6;
    const int wr = wave >> 2, wc = wave & 3;
    const int l16 = lane & 15, lh = lane >> 4;
    const int cw = wave * 2;
    const int NT = H / 64;

    // bijective XCD swizzle (m204), then rb-fastest decomposition
    const int nwg = gridDim.x;
    const int q = nwg >> 3, rres = nwg & 7;
    const int xcd = blockIdx.x & 7, idx = blockIdx.x >> 3;
    const int wgid = (xcd < rres ? xcd * (q + 1) : rres * (q + 1) + (xcd - rres) * q) + idx;
    const int rb = wgid % nrb, cb = wgid / nrb;
    const int brow = rb * 256, bcol = cb * 256;

    // per-lane staging source offsets (inverse of the read-side XOR swizzle)
    const size_t colp = (size_t)(((lane ^ (lane >> 3)) & 7) * 8);
    const size_t off0 = (size_t)((cw + 0) * 8 + (lane >> 3)) * H + colp;
    const size_t off1 = (size_t)((cw + 1) * 8 + (lane >> 3)) * H + colp;

    const uint16_t* X0 = Xb + (size_t)brow * H;
    const uint16_t* X1 = X0 + (size_t)128 * H;
    const uint16_t* W0 = Wb + (size_t)bcol * H;
    const uint16_t* W1 = W0 + (size_t)128 * H;

    f32x4 acc[2][2][4][2] = {};

    // ---- prologue: tile0 all 4 halves, tile1 first 3
    stage_half(X0 + off0, X0 + off1, ALDS(0, 0), cw);
    stage_half(W0 + off0, W0 + off1, BLDS(0, 0), cw);
    stage_half(X1 + off0, X1 + off1, ALDS(0, 1), cw);
    stage_half(W1 + off0, W1 + off1, BLDS(0, 1), cw);
    asm volatile("s_waitcnt vmcnt(4)" ::: "memory");
    stage_half(X0 + 64 + off0, X0 + 64 + off1, ALDS(1, 0), cw);
    stage_half(W0 + 64 + off0, W0 + 64 + off1, BLDS(1, 0), cw);
    stage_half(X1 + 64 + off0, X1 + 64 + off1, ALDS(1, 1), cw);
    asm volatile("s_waitcnt vmcnt(6)" ::: "memory");
    __builtin_amdgcn_s_barrier();

    for (int t = 0; t < NT; ++t) {
        const int buf = t & 1;
        const size_t k1 = (size_t)(t + 1) * 64;
        const size_t k2 = (size_t)(t + 2) * 64;
        bf16x8 a[4][2];
        bf16x8 b[2][2][2];

        // phase 0: quadrant (0,0); reads A0,B0; stages (t+1).B1 -> buf^1
        load_a(a, ALDS(buf, 0), wr, l16, lh);
        load_b(b[0], BLDS(buf, 0), wc, l16, lh);
        if (t + 1 < NT) stage_half(W1 + k1 + off0, W1 + k1 + off1, BLDS(buf ^ 1, 1), cw);
        phase_sync();
        mfma_quad<0, 0>(acc, a, b);
        __builtin_amdgcn_s_barrier();

        // phase 1: quadrant (0,1); reads B1; stages (t+2).A0 -> buf
        load_b(b[1], BLDS(buf, 1), wc, l16, lh);
        if (t + 2 < NT) stage_half(X0 + k2 + off0, X0 + k2 + off1, ALDS(buf, 0), cw);
        phase_sync();
        mfma_quad<0, 1>(acc, a, b);
        __builtin_amdgcn_s_barrier();

        // phase 2: quadrant (1,0); reads A1; stages (t+2).B0 -> buf
        load_a(a, ALDS(buf, 1), wr, l16, lh);
        if (t + 2 < NT) stage_half(W0 + k2 + off0, W0 + k2 + off1, BLDS(buf, 0), cw);
        phase_sync();
        mfma_quad<1, 0>(acc, a, b);
        __builtin_amdgcn_s_barrier();

        // phase 3: quadrant (1,1); no new reads; stages (t+2).A1 -> buf
        if (t + 2 < NT) stage_half(X1 + k2 + off0, X1 + k2 + off1, ALDS(buf, 1), cw);
        phase_sync();
        mfma_quad<1, 1>(acc, a, b);
        if (t + 2 < NT) asm volatile("s_waitcnt vmcnt(6)" ::: "memory");
        else            asm volatile("s_waitcnt vmcnt(0)" ::: "memory");
        __builtin_amdgcn_s_barrier();
    }

    // ---- epilogue: per-row max / sumexp over this tile's 256 cols + target pick
    __syncthreads();  // full drain; smem reused below
    float (*red_m)[4] = (float(*)[4])smem;
    float (*red_s)[4] = (float(*)[4])(smem + 4096);
    int* tgt_l = (int*)(smem + 8192);
    if (tid < 256) {
        long long tt = target[brow + tid];
        if (tt < 0) tt = 0;
        if (tt >= V) tt = (long long)V - 1;
        tgt_l[tid] = (int)tt;
    }
    __syncthreads();

#pragma unroll
    for (int mh = 0; mh < 2; ++mh)
#pragma unroll
        for (int mi = 0; mi < 4; ++mi)
#pragma unroll
            for (int r = 0; r < 4; ++r) {
                int row = mh * 128 + wr * 64 + mi * 16 + lh * 4 + r;
                int tc = tgt_l[row] - bcol;
                float mx = -INFINITY;
#pragma unroll
                for (int nh = 0; nh < 2; ++nh)
#pragma unroll
                    for (int ni = 0; ni < 2; ++ni) {
                        float v = acc[mh][nh][mi][ni][r];
                        int col = nh * 128 + wc * 32 + ni * 16 + l16;
                        if (tc == col) tgt_logit[brow + row] = v;
                        mx = fmaxf(mx, v);
                    }
#pragma unroll
                for (int d = 1; d < 16; d <<= 1) mx = fmaxf(mx, __shfl_xor(mx, d));
                float s = 0.f;
#pragma unroll
                for (int nh = 0; nh < 2; ++nh)
#pragma unroll
                    for (int ni = 0; ni < 2; ++ni)
                        s += __expf(acc[mh][nh][mi][ni][r] - mx);
#pragma unroll
                for (int d = 1; d < 16; d <<= 1) s += __shfl_xor(s, d);
                if (l16 == 0) { red_m[row][wc] = mx; red_s[row][wc] = s; }
            }
    __syncthreads();
    if (tid < 256) {
        float m0 = red_m[tid][0], m1 = red_m[tid][1];
        float m2 = red_m[tid][2], m3 = red_m[tid][3];
        float M = fmaxf(fmaxf(m0, m1), fmaxf(m2, m3));
        float S = red_s[tid][0] * __expf(m0 - M) + red_s[tid][1] * __expf(m1 - M)
                + red_s[tid][2] * __expf(m2 - M) + red_s[tid][3] * __expf(m3 - M);
        partials[(size_t)cb * BT + brow + tid] = make_float2(M, S);
    }
#undef ALDS
#undef BLDS
}

// ---------------------------------------------------------------- fp32 fallback (128^2, m97 structure)
__global__ void flce_gemm_f32(const float* __restrict__ X, const float* __restrict__ Wf,
                              const long long* __restrict__ target,
                              float2* __restrict__ partials, float* __restrict__ tgt_logit,
                              int BT, int H, int V, int nrb) {
    __shared__ uint16_t As[128 * 32];
    __shared__ uint16_t Bs[128 * 32];
    __shared__ float red_m[128][2];
    __shared__ float red_s[128][2];
    __shared__ int tgt_l[128];

    const int tid = threadIdx.x;
    const int wave = tid >> 6, lane = tid & 63;
    const int wr = wave >> 1, wc = wave & 1;
    const int l16 = lane & 15, lh = lane >> 4;
    const int bid = blockIdx.x;
    const int rb = bid % nrb, cb = bid / nrb;
    const int brow = rb * 128, bcol = cb * 128;

    if (tid < 128) {
        long long t = target[brow + tid];
        if (t < 0) t = 0;
        if (t >= V) t = (long long)V - 1;
        tgt_l[tid] = (int)t;
    }

    f32x4 acc[4][4] = {};
    for (int k0 = 0; k0 < H; k0 += 32) {
        __syncthreads();
#pragma unroll
        for (int j = 0; j < 4; ++j) {
            int fi = tid + j * 256;
            int row = fi >> 3;
            int kk = (fi & 7) << 2;
            float4 av = *(const float4*)(X + (size_t)(brow + row) * H + k0 + kk);
            float4 bv = *(const float4*)(Wf + (size_t)(bcol + row) * H + k0 + kk);
            u16x4 au, bu;
            au[0] = f2b(av.x); au[1] = f2b(av.y); au[2] = f2b(av.z); au[3] = f2b(av.w);
            bu[0] = f2b(bv.x); bu[1] = f2b(bv.y); bu[2] = f2b(bv.z); bu[3] = f2b(bv.w);
            *(u16x4*)&As[row * 32 + kk] = au;
            *(u16x4*)&Bs[row * 32 + kk] = bu;
        }
        __syncthreads();
        bf16x8 af[4], bf[4];
#pragma unroll
        for (int m = 0; m < 4; ++m)
            af[m] = *(const bf16x8*)&As[(wr * 64 + m * 16 + l16) * 32 + lh * 8];
#pragma unroll
        for (int n = 0; n < 4; ++n)
            bf[n] = *(const bf16x8*)&Bs[(wc * 64 + n * 16 + l16) * 32 + lh * 8];
#pragma unroll
        for (int m = 0; m < 4; ++m)
#pragma unroll
            for (int n = 0; n < 4; ++n)
                acc[m][n] = __builtin_amdgcn_mfma_f32_16x16x32_bf16(af[m], bf[n], acc[m][n], 0, 0, 0);
    }
#pragma unroll
    for (int m = 0; m < 4; ++m) {
#pragma unroll
        for (int r = 0; r < 4; ++r) {
            int rowl = wr * 64 + m * 16 + lh * 4 + r;
            int tc = tgt_l[rowl] - bcol;
            float mx = -INFINITY;
#pragma unroll
            for (int n = 0; n < 4; ++n) {
                float v = acc[m][n][r];
                if (tc == wc * 64 + n * 16 + l16) tgt_logit[brow + rowl] = v;
                mx = fmaxf(mx, v);
            }
#pragma unroll
            for (int d = 1; d < 16; d <<= 1) mx = fmaxf(mx, __shfl_xor(mx, d));
            float s = 0.f;
#pragma unroll
            for (int n = 0; n < 4; ++n) s += __expf(acc[m][n][r] - mx);
#pragma unroll
            for (int d = 1; d < 16; d <<= 1) s += __shfl_xor(s, d);
            if (l16 == 0) { red_m[rowl][wc] = mx; red_s[rowl][wc] = s; }
        }
    }
    __syncthreads();
    if (tid < 128) {
        float m0 = red_m[tid][0], m1 = red_m[tid][1];
        float s0 = red_s[tid][0], s1 = red_s[tid][1];
        float M = fmaxf(m0, m1);
        float S = s0 * __expf(m0 - M) + s1 * __expf(m1 - M);
        partials[(size_t)cb * BT + brow + tid] = make_float2(M, S);
    }
}

// ---------------------------------------------------------------- per-row LSE merge + block sums
__global__ void flce_reduce(const float2* __restrict__ partials,
                            const float* __restrict__ tgt_logit,
                            const long long* __restrict__ target,
                            float2* __restrict__ bsums, int BT, int NCB) {
    int row = blockIdx.x * blockDim.x + threadIdx.x;
    float M = -INFINITY, S = 0.f;
    for (int cbi = 0; cbi < NCB; ++cbi) {
        float2 p = partials[(size_t)cbi * BT + row];
        float Mn = fmaxf(M, p.x);
        S = S * __expf(M - Mn) + p.y * __expf(p.x - Mn);
        M = Mn;
    }
    float lse = M + __logf(S);
    bool valid = (target[row] != -100);
    float nll = valid ? (lse - tgt_logit[row]) : 0.f;
    float cnt = valid ? 1.f : 0.f;
#pragma unroll
    for (int d = 1; d < 64; d <<= 1) { nll += __shfl_xor(nll, d); cnt += __shfl_xor(cnt, d); }
    __shared__ float sm[8][2];
    int w = threadIdx.x >> 6;
    if ((threadIdx.x & 63) == 0) { sm[w][0] = nll; sm[w][1] = cnt; }
    __syncthreads();
    if (threadIdx.x == 0) {
        float sn = 0.f, sc = 0.f;
        int nw = blockDim.x >> 6;
        for (int i = 0; i < nw; ++i) { sn += sm[i][0]; sc += sm[i][1]; }
        bsums[blockIdx.x] = make_float2(sn, sc);
    }
}

__global__ void flce_final(const float2* __restrict__ bsums, int nb, float* __restrict__ out) {
    if (blockIdx.x == 0 && threadIdx.x == 0) {
        float sn = 0.f, sc = 0.f;
        for (int i = 0; i < nb; ++i) { sn += bsums[i].x; sc += bsums[i].y; }
        out[0] = sn / sc;
    }
}

// ---------------------------------------------------------------- launch
extern "C" void kernel_launch(void* const* d_in, const int* in_sizes, int n_in,
                              void* d_out, int out_size, void* d_ws, size_t ws_size,
                              hipStream_t stream) {
    const float* x = (const float*)d_in[0];
    const float* w = (const float*)d_in[1];
    const long long* target = (const long long*)d_in[2];
    float* out = (float*)d_out;

    const int BT = in_sizes[2];
    const int H = in_sizes[0] / BT;
    const int V = in_sizes[1] / H;
    const int nred = BT / 256;

    char* ws = (char*)d_ws;
    size_t szW = (size_t)V * H * sizeof(uint16_t);
    size_t szX = (size_t)BT * H * sizeof(uint16_t);
    const int nrb = BT / 256;         // 16
    const int ncb = V / 256;          // 125
    size_t szPart = (size_t)ncb * BT * sizeof(float2);
    size_t szTgt = (size_t)BT * sizeof(float);
    size_t szB = (size_t)nred * sizeof(float2);

    bool use16 = ws_size >= szW + szX + szPart + szTgt + szB;

    if (use16) {
        uint16_t* Wb = (uint16_t*)ws;
        uint16_t* Xb = (uint16_t*)(ws + szW);
        float2* partials = (float2*)(ws + szW + szX);
        float* tgtlog = (float*)(ws + szW + szX + szPart);
        float2* bsums = (float2*)(ws + szW + szX + szPart + szTgt);

        hipLaunchKernelGGL(cvt_kernel, dim3(1024), dim3(256), 0, stream,
                           x, Xb, (size_t)BT * H / 8);
        hipLaunchKernelGGL(cvt_kernel, dim3(4096), dim3(256), 0, stream,
                           w, Wb, (size_t)V * H / 8);
        hipLaunchKernelGGL(flce_gemm8, dim3(nrb * ncb), dim3(512), 0, stream,
                           Xb, Wb, target, partials, tgtlog, BT, H, V, nrb);
        hipLaunchKernelGGL(flce_reduce, dim3(BT / 256), dim3(256), 0, stream,
                           partials, tgtlog, target, bsums, BT, ncb);
        hipLaunchKernelGGL(flce_final, dim3(1), dim3(64), 0, stream, bsums, nred, out);
    } else {
        const int nrb1 = BT / 128, ncb1 = V / 128;
        float2* partials = (float2*)ws;
        float* tgtlog = (float*)(ws + (size_t)ncb1 * BT * sizeof(float2));
        float2* bsums = (float2*)(ws + (size_t)ncb1 * BT * sizeof(float2) + szTgt);
        hipLaunchKernelGGL(flce_gemm_f32, dim3(nrb1 * ncb1), dim3(256), 0, stream,
                           x, w, target, partials, tgtlog, BT, H, V, nrb1);
        hipLaunchKernelGGL(flce_reduce, dim3(BT / 256), dim3(256), 0, stream,
                           partials, tgtlog, target, bsums, BT, ncb1);
        hipLaunchKernelGGL(flce_final, dim3(1), dim3(64), 0, stream, bsums, nred, out);
    }
}

// Round 3
// 1108.240 us; speedup vs baseline: 1.2855x; 1.0442x over previous
//
#include <hip/hip_runtime.h>
#include <hip/hip_bf16.h>
#include <cstdint>
#include <cstddef>

typedef __attribute__((ext_vector_type(8))) short bf16x8;
typedef __attribute__((ext_vector_type(4))) float f32x4;
typedef __attribute__((ext_vector_type(4))) uint16_t u16x4;
typedef __attribute__((ext_vector_type(8))) uint16_t u16x8;

#define GLOBAL_AS __attribute__((address_space(1)))
#define LDS_AS __attribute__((address_space(3)))

__device__ inline uint16_t f2b(float f) {
    uint32_t x = __float_as_uint(f);
    uint32_t r = (x + 0x7fffu + ((x >> 16) & 1u)) >> 16;
    return (uint16_t)r;
}

// ---------------------------------------------------------------- convert fp32 -> bf16
__global__ void cvt_kernel(const float* __restrict__ in, uint16_t* __restrict__ out,
                           size_t n8) {
    size_t stride = (size_t)gridDim.x * blockDim.x;
    for (size_t i = (size_t)blockIdx.x * blockDim.x + threadIdx.x; i < n8; i += stride) {
        const float4* p = (const float4*)(in + i * 8);
        float4 a = p[0], b = p[1];
        u16x8 o;
        o[0] = f2b(a.x); o[1] = f2b(a.y); o[2] = f2b(a.z); o[3] = f2b(a.w);
        o[4] = f2b(b.x); o[5] = f2b(b.y); o[6] = f2b(b.z); o[7] = f2b(b.w);
        *(u16x8*)(out + i * 8) = o;
    }
}

// ---------------------------------------------------------------- 8-phase 256x256 fused GEMM+LSE
// T2 read-side swizzle: linear byte offset o (128B rows) -> o ^ ((row&7)<<4).
// Staged via inverse-permuted global source + linear global_load_lds dest.
// R3: fragment ds_reads software-pipelined one phase early (issued post-MFMA,
// consumed after the next barrier) — removes the post-barrier lgkmcnt stall.

__device__ __forceinline__ void stage_half(const uint16_t* g0, const uint16_t* g1,
                                           uint16_t* region, int chunk0) {
    __builtin_amdgcn_global_load_lds((const GLOBAL_AS uint32_t*)g0,
                                     (LDS_AS uint32_t*)(region + chunk0 * 512), 16, 0, 0);
    __builtin_amdgcn_global_load_lds((const GLOBAL_AS uint32_t*)g1,
                                     (LDS_AS uint32_t*)(region + (chunk0 + 1) * 512), 16, 0, 0);
}

__device__ __forceinline__ void load_a(bf16x8 a[4][2], const uint16_t* region,
                                       int wr, int l16, int lh) {
    const int xorv = (l16 & 7) << 4;
#pragma unroll
    for (int mi = 0; mi < 4; ++mi) {
        const char* rowp = (const char*)region + (wr * 64 + mi * 16 + l16) * 128;
#pragma unroll
        for (int kk = 0; kk < 2; ++kk)
            a[mi][kk] = *(const bf16x8*)(rowp + ((kk * 64 + lh * 16) ^ xorv));
    }
}

__device__ __forceinline__ void load_b(bf16x8 b[2][2], const uint16_t* region,
                                       int wc, int l16, int lh) {
    const int xorv = (l16 & 7) << 4;
#pragma unroll
    for (int ni = 0; ni < 2; ++ni) {
        const char* rowp = (const char*)region + (wc * 32 + ni * 16 + l16) * 128;
#pragma unroll
        for (int kk = 0; kk < 2; ++kk)
            b[ni][kk] = *(const bf16x8*)(rowp + ((kk * 64 + lh * 16) ^ xorv));
    }
}

template <int MH, int NH>
__device__ __forceinline__ void mfma_quad(f32x4 acc[2][2][4][2], const bf16x8 a[4][2],
                                          const bf16x8 b[2][2]) {
    __builtin_amdgcn_s_setprio(1);
#pragma unroll
    for (int mi = 0; mi < 4; ++mi)
#pragma unroll
        for (int ni = 0; ni < 2; ++ni)
#pragma unroll
            for (int kk = 0; kk < 2; ++kk)
                acc[MH][NH][mi][ni] = __builtin_amdgcn_mfma_f32_16x16x32_bf16(
                    a[mi][kk], b[ni][kk], acc[MH][NH][mi][ni], 0, 0, 0);
    __builtin_amdgcn_s_setprio(0);
}

__global__ __launch_bounds__(512, 2)
void flce_gemm8(const uint16_t* __restrict__ Xb, const uint16_t* __restrict__ Wb,
                const long long* __restrict__ target,
                float2* __restrict__ partials, float* __restrict__ tgt_logit,
                int BT, int H, int V, int nrb) {
    __shared__ __align__(16) char smem[131072];   // A: 4 regions x 16KB, B: same
    uint16_t* Ab = (uint16_t*)smem;
    uint16_t* Bb = (uint16_t*)(smem + 65536);
#define ALDS(bf, hf) (Ab + ((bf) * 2 + (hf)) * 8192)
#define BLDS(bf, hf) (Bb + ((bf) * 2 + (hf)) * 8192)

    const int tid = threadIdx.x;
    const int lane = tid & 63, wave = tid >> 6;
    const int wr = wave >> 2, wc = wave & 3;
    const int l16 = lane & 15, lh = lane >> 4;
    const int cw = wave * 2;
    const int NT = H / 64;

    // bijective XCD swizzle (m204), then rb-fastest decomposition
    const int nwg = gridDim.x;
    const int q = nwg >> 3, rres = nwg & 7;
    const int xcd = blockIdx.x & 7, idx = blockIdx.x >> 3;
    const int wgid = (xcd < rres ? xcd * (q + 1) : rres * (q + 1) + (xcd - rres) * q) + idx;
    const int rb = wgid % nrb, cb = wgid / nrb;
    const int brow = rb * 256, bcol = cb * 256;

    // per-lane staging source offsets (inverse of the read-side XOR swizzle)
    const size_t colp = (size_t)(((lane ^ (lane >> 3)) & 7) * 8);
    const size_t off0 = (size_t)((cw + 0) * 8 + (lane >> 3)) * H + colp;
    const size_t off1 = (size_t)((cw + 1) * 8 + (lane >> 3)) * H + colp;

    const uint16_t* X0 = Xb + (size_t)brow * H;
    const uint16_t* X1 = X0 + (size_t)128 * H;
    const uint16_t* W0 = Wb + (size_t)bcol * H;
    const uint16_t* W1 = W0 + (size_t)128 * H;

    f32x4 acc[2][2][4][2] = {};
    bf16x8 a[4][2];      // rotates: A0(t) -> A1(t) -> A0(t+1)
    bf16x8 b0f[2][2];    // B0(t) -> B0(t+1)
    bf16x8 b1f[2][2];    // B1(t)

    // ---- prologue: tile0 all 4 halves, tile1 first 3 (invariant: 6 outstanding)
    stage_half(X0 + off0, X0 + off1, ALDS(0, 0), cw);
    stage_half(W0 + off0, W0 + off1, BLDS(0, 0), cw);
    stage_half(X1 + off0, X1 + off1, ALDS(0, 1), cw);
    stage_half(W1 + off0, W1 + off1, BLDS(0, 1), cw);
    if (NT > 1) {
        asm volatile("s_waitcnt vmcnt(4)" ::: "memory");
        stage_half(X0 + 64 + off0, X0 + 64 + off1, ALDS(1, 0), cw);
        stage_half(W0 + 64 + off0, W0 + 64 + off1, BLDS(1, 0), cw);
        stage_half(X1 + 64 + off0, X1 + 64 + off1, ALDS(1, 1), cw);
        asm volatile("s_waitcnt vmcnt(6)" ::: "memory");
    } else {
        asm volatile("s_waitcnt vmcnt(0)" ::: "memory");
    }
    __builtin_amdgcn_s_barrier();
    // pre-read tile0 phase-0 fragments
    load_a(a, ALDS(0, 0), wr, l16, lh);
    load_b(b0f, BLDS(0, 0), wc, l16, lh);

#pragma unroll 2
    for (int t = 0; t < NT; ++t) {
        const int buf = t & 1;
        const size_t k1 = (size_t)(t + 1) * 64;
        const size_t k2 = (size_t)(t + 2) * 64;
        const bool deep = (t + 2 < NT);

        // phase 0: MFMA (A0,B0); stage (t+1).B1; pre-read B1(t) frags
        mfma_quad<0, 0>(acc, a, b0f);
        if (t + 1 < NT) stage_half(W1 + k1 + off0, W1 + k1 + off1, BLDS(buf ^ 1, 1), cw);
        load_b(b1f, BLDS(buf, 1), wc, l16, lh);
        __builtin_amdgcn_s_barrier();

        // phase 1: MFMA (A0,B1); stage (t+2).A0; pre-read A1(t) frags (reuse a)
        mfma_quad<0, 1>(acc, a, b1f);
        if (deep) stage_half(X0 + k2 + off0, X0 + k2 + off1, ALDS(buf, 0), cw);
        load_a(a, ALDS(buf, 1), wr, l16, lh);
        __builtin_amdgcn_s_barrier();

        // phase 2: MFMA (A1,B0); stage (t+2).B0; W2 drains (t+1).{A0,B0,A1}
        mfma_quad<1, 0>(acc, a, b0f);
        if (deep) {
            stage_half(W0 + k2 + off0, W0 + k2 + off1, BLDS(buf, 0), cw);
            asm volatile("s_waitcnt vmcnt(6)" ::: "memory");
        } else {
            asm volatile("s_waitcnt vmcnt(0)" ::: "memory");
        }
        __builtin_amdgcn_s_barrier();

        // phase 3: MFMA (A1,B1); stage (t+2).A1; W3 drains (t+1).B1;
        //          pre-read (t+1) phase-0 frags (reuse a, b0f)
        mfma_quad<1, 1>(acc, a, b1f);
        if (deep) {
            stage_half(X1 + k2 + off0, X1 + k2 + off1, ALDS(buf, 1), cw);
            asm volatile("s_waitcnt vmcnt(6)" ::: "memory");
        } else {
            asm volatile("s_waitcnt vmcnt(0)" ::: "memory");
        }
        if (t + 1 < NT) {
            load_a(a, ALDS(buf ^ 1, 0), wr, l16, lh);
            load_b(b0f, BLDS(buf ^ 1, 0), wc, l16, lh);
        }
        __builtin_amdgcn_s_barrier();
    }

    // ---- epilogue: per-row max / sumexp over this tile's 256 cols + target pick
    __syncthreads();  // full drain; smem reused below
    float (*red_m)[4] = (float(*)[4])smem;
    float (*red_s)[4] = (float(*)[4])(smem + 4096);
    int* tgt_l = (int*)(smem + 8192);
    if (tid < 256) {
        long long tt = target[brow + tid];
        if (tt < 0) tt = 0;
        if (tt >= V) tt = (long long)V - 1;
        tgt_l[tid] = (int)tt;
    }
    __syncthreads();

#pragma unroll
    for (int mh = 0; mh < 2; ++mh)
#pragma unroll
        for (int mi = 0; mi < 4; ++mi)
#pragma unroll
            for (int r = 0; r < 4; ++r) {
                int row = mh * 128 + wr * 64 + mi * 16 + lh * 4 + r;
                int tc = tgt_l[row] - bcol;
                float mx = -INFINITY;
#pragma unroll
                for (int nh = 0; nh < 2; ++nh)
#pragma unroll
                    for (int ni = 0; ni < 2; ++ni) {
                        float v = acc[mh][nh][mi][ni][r];
                        int col = nh * 128 + wc * 32 + ni * 16 + l16;
                        if (tc == col) tgt_logit[brow + row] = v;
                        mx = fmaxf(mx, v);
                    }
#pragma unroll
                for (int d = 1; d < 16; d <<= 1) mx = fmaxf(mx, __shfl_xor(mx, d));
                float s = 0.f;
#pragma unroll
                for (int nh = 0; nh < 2; ++nh)
#pragma unroll
                    for (int ni = 0; ni < 2; ++ni)
                        s += __expf(acc[mh][nh][mi][ni][r] - mx);
#pragma unroll
                for (int d = 1; d < 16; d <<= 1) s += __shfl_xor(s, d);
                if (l16 == 0) { red_m[row][wc] = mx; red_s[row][wc] = s; }
            }
    __syncthreads();
    if (tid < 256) {
        float m0 = red_m[tid][0], m1 = red_m[tid][1];
        float m2 = red_m[tid][2], m3 = red_m[tid][3];
        float M = fmaxf(fmaxf(m0, m1), fmaxf(m2, m3));
        float S = red_s[tid][0] * __expf(m0 - M) + red_s[tid][1] * __expf(m1 - M)
                + red_s[tid][2] * __expf(m2 - M) + red_s[tid][3] * __expf(m3 - M);
        partials[(size_t)cb * BT + brow + tid] = make_float2(M, S);
    }
#undef ALDS
#undef BLDS
}

// ---------------------------------------------------------------- fp32 fallback (128^2, m97 structure)
__global__ void flce_gemm_f32(const float* __restrict__ X, const float* __restrict__ Wf,
                              const long long* __restrict__ target,
                              float2* __restrict__ partials, float* __restrict__ tgt_logit,
                              int BT, int H, int V, int nrb) {
    __shared__ uint16_t As[128 * 32];
    __shared__ uint16_t Bs[128 * 32];
    __shared__ float red_m[128][2];
    __shared__ float red_s[128][2];
    __shared__ int tgt_l[128];

    const int tid = threadIdx.x;
    const int wave = tid >> 6, lane = tid & 63;
    const int wr = wave >> 1, wc = wave & 1;
    const int l16 = lane & 15, lh = lane >> 4;
    const int bid = blockIdx.x;
    const int rb = bid % nrb, cb = bid / nrb;
    const int brow = rb * 128, bcol = cb * 128;

    if (tid < 128) {
        long long t = target[brow + tid];
        if (t < 0) t = 0;
        if (t >= V) t = (long long)V - 1;
        tgt_l[tid] = (int)t;
    }

    f32x4 acc[4][4] = {};
    for (int k0 = 0; k0 < H; k0 += 32) {
        __syncthreads();
#pragma unroll
        for (int j = 0; j < 4; ++j) {
            int fi = tid + j * 256;
            int row = fi >> 3;
            int kk = (fi & 7) << 2;
            float4 av = *(const float4*)(X + (size_t)(brow + row) * H + k0 + kk);
            float4 bv = *(const float4*)(Wf + (size_t)(bcol + row) * H + k0 + kk);
            u16x4 au, bu;
            au[0] = f2b(av.x); au[1] = f2b(av.y); au[2] = f2b(av.z); au[3] = f2b(av.w);
            bu[0] = f2b(bv.x); bu[1] = f2b(bv.y); bu[2] = f2b(bv.z); bu[3] = f2b(bv.w);
            *(u16x4*)&As[row * 32 + kk] = au;
            *(u16x4*)&Bs[row * 32 + kk] = bu;
        }
        __syncthreads();
        bf16x8 af[4], bf[4];
#pragma unroll
        for (int m = 0; m < 4; ++m)
            af[m] = *(const bf16x8*)&As[(wr * 64 + m * 16 + l16) * 32 + lh * 8];
#pragma unroll
        for (int n = 0; n < 4; ++n)
            bf[n] = *(const bf16x8*)&Bs[(wc * 64 + n * 16 + l16) * 32 + lh * 8];
#pragma unroll
        for (int m = 0; m < 4; ++m)
#pragma unroll
            for (int n = 0; n < 4; ++n)
                acc[m][n] = __builtin_amdgcn_mfma_f32_16x16x32_bf16(af[m], bf[n], acc[m][n], 0, 0, 0);
    }
#pragma unroll
    for (int m = 0; m < 4; ++m) {
#pragma unroll
        for (int r = 0; r < 4; ++r) {
            int rowl = wr * 64 + m * 16 + lh * 4 + r;
            int tc = tgt_l[rowl] - bcol;
            float mx = -INFINITY;
#pragma unroll
            for (int n = 0; n < 4; ++n) {
                float v = acc[m][n][r];
                if (tc == wc * 64 + n * 16 + l16) tgt_logit[brow + rowl] = v;
                mx = fmaxf(mx, v);
            }
#pragma unroll
            for (int d = 1; d < 16; d <<= 1) mx = fmaxf(mx, __shfl_xor(mx, d));
            float s = 0.f;
#pragma unroll
            for (int n = 0; n < 4; ++n) s += __expf(acc[m][n][r] - mx);
#pragma unroll
            for (int d = 1; d < 16; d <<= 1) s += __shfl_xor(s, d);
            if (l16 == 0) { red_m[rowl][wc] = mx; red_s[rowl][wc] = s; }
        }
    }
    __syncthreads();
    if (tid < 128) {
        float m0 = red_m[tid][0], m1 = red_m[tid][1];
        float s0 = red_s[tid][0], s1 = red_s[tid][1];
        float M = fmaxf(m0, m1);
        float S = s0 * __expf(m0 - M) + s1 * __expf(m1 - M);
        partials[(size_t)cb * BT + brow + tid] = make_float2(M, S);
    }
}

// ---------------------------------------------------------------- per-row LSE merge + block sums
__global__ void flce_reduce(const float2* __restrict__ partials,
                            const float* __restrict__ tgt_logit,
                            const long long* __restrict__ target,
                            float2* __restrict__ bsums, int BT, int NCB) {
    int row = blockIdx.x * blockDim.x + threadIdx.x;
    float M = -INFINITY, S = 0.f;
    for (int cbi = 0; cbi < NCB; ++cbi) {
        float2 p = partials[(size_t)cbi * BT + row];
        float Mn = fmaxf(M, p.x);
        S = S * __expf(M - Mn) + p.y * __expf(p.x - Mn);
        M = Mn;
    }
    float lse = M + __logf(S);
    bool valid = (target[row] != -100);
    float nll = valid ? (lse - tgt_logit[row]) : 0.f;
    float cnt = valid ? 1.f : 0.f;
#pragma unroll
    for (int d = 1; d < 64; d <<= 1) { nll += __shfl_xor(nll, d); cnt += __shfl_xor(cnt, d); }
    __shared__ float sm[8][2];
    int w = threadIdx.x >> 6;
    if ((threadIdx.x & 63) == 0) { sm[w][0] = nll; sm[w][1] = cnt; }
    __syncthreads();
    if (threadIdx.x == 0) {
        float sn = 0.f, sc = 0.f;
        int nw = blockDim.x >> 6;
        for (int i = 0; i < nw; ++i) { sn += sm[i][0]; sc += sm[i][1]; }
        bsums[blockIdx.x] = make_float2(sn, sc);
    }
}

__global__ void flce_final(const float2* __restrict__ bsums, int nb, float* __restrict__ out) {
    if (blockIdx.x == 0 && threadIdx.x == 0) {
        float sn = 0.f, sc = 0.f;
        for (int i = 0; i < nb; ++i) { sn += bsums[i].x; sc += bsums[i].y; }
        out[0] = sn / sc;
    }
}

// ---------------------------------------------------------------- launch
extern "C" void kernel_launch(void* const* d_in, const int* in_sizes, int n_in,
                              void* d_out, int out_size, void* d_ws, size_t ws_size,
                              hipStream_t stream) {
    const float* x = (const float*)d_in[0];
    const float* w = (const float*)d_in[1];
    const long long* target = (const long long*)d_in[2];
    float* out = (float*)d_out;

    const int BT = in_sizes[2];
    const int H = in_sizes[0] / BT;
    const int V = in_sizes[1] / H;
    const int nred = BT / 256;

    char* ws = (char*)d_ws;
    size_t szW = (size_t)V * H * sizeof(uint16_t);
    size_t szX = (size_t)BT * H * sizeof(uint16_t);
    const int nrb = BT / 256;         // 16
    const int ncb = V / 256;          // 125
    size_t szPart = (size_t)ncb * BT * sizeof(float2);
    size_t szTgt = (size_t)BT * sizeof(float);
    size_t szB = (size_t)nred * sizeof(float2);

    bool use16 = ws_size >= szW + szX + szPart + szTgt + szB;

    if (use16) {
        uint16_t* Wb = (uint16_t*)ws;
        uint16_t* Xb = (uint16_t*)(ws + szW);
        float2* partials = (float2*)(ws + szW + szX);
        float* tgtlog = (float*)(ws + szW + szX + szPart);
        float2* bsums = (float2*)(ws + szW + szX + szPart + szTgt);

        hipLaunchKernelGGL(cvt_kernel, dim3(1024), dim3(256), 0, stream,
                           x, Xb, (size_t)BT * H / 8);
        hipLaunchKernelGGL(cvt_kernel, dim3(4096), dim3(256), 0, stream,
                           w, Wb, (size_t)V * H / 8);
        hipLaunchKernelGGL(flce_gemm8, dim3(nrb * ncb), dim3(512), 0, stream,
                           Xb, Wb, target, partials, tgtlog, BT, H, V, nrb);
        hipLaunchKernelGGL(flce_reduce, dim3(BT / 256), dim3(256), 0, stream,
                           partials, tgtlog, target, bsums, BT, ncb);
        hipLaunchKernelGGL(flce_final, dim3(1), dim3(64), 0, stream, bsums, nred, out);
    } else {
        const int nrb1 = BT / 128, ncb1 = V / 128;
        float2* partials = (float2*)ws;
        float* tgtlog = (float*)(ws + (size_t)ncb1 * BT * sizeof(float2));
        float2* bsums = (float2*)(ws + (size_t)ncb1 * BT * sizeof(float2) + szTgt);
        hipLaunchKernelGGL(flce_gemm_f32, dim3(nrb1 * ncb1), dim3(256), 0, stream,
                           x, w, target, partials, tgtlog, BT, H, V, nrb1);
        hipLaunchKernelGGL(flce_reduce, dim3(BT / 256), dim3(256), 0, stream,
                           partials, tgtlog, target, bsums, BT, ncb1);
        hipLaunchKernelGGL(flce_final, dim3(1), dim3(64), 0, stream, bsums, nred, out);
    }
}

// Round 4
// 961.909 us; speedup vs baseline: 1.4811x; 1.1521x over previous
//
#include <hip/hip_runtime.h>
#include <hip/hip_bf16.h>
#include <cstdint>
#include <cstddef>

typedef __attribute__((ext_vector_type(8))) short bf16x8;
typedef __attribute__((ext_vector_type(4))) float f32x4;
typedef __attribute__((ext_vector_type(16))) float f32x16;
typedef __attribute__((ext_vector_type(4))) int i32x4;
typedef __attribute__((ext_vector_type(8))) int i32x8;
typedef __attribute__((ext_vector_type(4))) uint16_t u16x4;
typedef __attribute__((ext_vector_type(8))) uint16_t u16x8;

#define GLOBAL_AS __attribute__((address_space(1)))
#define LDS_AS __attribute__((address_space(3)))

__device__ inline uint16_t f2b(float f) {
    uint32_t x = __float_as_uint(f);
    uint32_t r = (x + 0x7fffu + ((x >> 16) & 1u)) >> 16;
    return (uint16_t)r;
}

// ---------------------------------------------------------------- convert fp32 -> fp8 e4m3 (x64 prescale)
__global__ void cvt8_kernel(const float* __restrict__ in, uint2* __restrict__ out, size_t n8) {
    size_t stride = (size_t)gridDim.x * blockDim.x;
    for (size_t i = (size_t)blockIdx.x * blockDim.x + threadIdx.x; i < n8; i += stride) {
        const float4* p = (const float4*)(in + i * 8);
        float4 a = p[0], b = p[1];
        int w0 = __builtin_amdgcn_cvt_pk_fp8_f32(a.x * 64.f, a.y * 64.f, 0, false);
        w0 = __builtin_amdgcn_cvt_pk_fp8_f32(a.z * 64.f, a.w * 64.f, w0, true);
        int w1 = __builtin_amdgcn_cvt_pk_fp8_f32(b.x * 64.f, b.y * 64.f, 0, false);
        w1 = __builtin_amdgcn_cvt_pk_fp8_f32(b.z * 64.f, b.w * 64.f, w1, true);
        out[i] = make_uint2((unsigned)w0, (unsigned)w1);
    }
}

// ---------------------------------------------------------------- fp8 MX GEMM + fused LSE partials
// 256x256 tile, BK=64, 8 waves (2x4), 32x32x64 f8f6f4 MFMA, identity HW scales,
// epilogue descales by 1/4096 (inputs prescaled by 64 each).
// LDS regions: A(buf,mh)/B(buf,nh) = 128 rows x 64 B, XOR swizzle slot^=(row&3).

#define SC8 0x7F7F7F7F

__device__ __forceinline__ i32x8 frag_read(const char* region, int lr, int kb) {
    const int swz = (lr & 3) << 4;
    const char* rp = region + lr * 64;
    i32x4 lo = *(const i32x4*)(rp + (kb ^ swz));
    i32x4 hi = *(const i32x4*)(rp + ((kb + 16) ^ swz));
    i32x8 f;
    f[0] = lo[0]; f[1] = lo[1]; f[2] = lo[2]; f[3] = lo[3];
    f[4] = hi[0]; f[5] = hi[1]; f[6] = hi[2]; f[7] = hi[3];
    return f;
}

#define MFMA8(aa, bb, cc) cc = __builtin_amdgcn_mfma_scale_f32_32x32x64_f8f6f4( \
        aa, bb, cc, 0, 0, 0, SC8, 0, SC8)

__global__ __launch_bounds__(512, 2)
void flce_gemm_fp8(const uint8_t* __restrict__ X8, const uint8_t* __restrict__ W8,
                   const long long* __restrict__ target,
                   float2* __restrict__ partials, float* __restrict__ tgt_logit,
                   int BT, int H, int V, int nrb) {
    __shared__ __align__(16) char smem[65536];
    char* Ab = smem;            // 4 regions x 8 KB: (buf*2+mh)
    char* Bb = smem + 32768;
#define AR(bf, hf) (Ab + ((bf) * 2 + (hf)) * 8192)
#define BR(bf, hf) (Bb + ((bf) * 2 + (hf)) * 8192)

    const int tid = threadIdx.x;
    const int lane = tid & 63, wave = tid >> 6;
    const int wr = wave >> 2, wc = wave & 3;
    const int l31 = lane & 31;
    const int kb = (lane >> 5) * 32;      // fragment k-byte base
    const int NT = H / 64;

    // bijective XCD swizzle (m204), rb-fastest
    const int nwg = gridDim.x;
    const int q = nwg >> 3, rres = nwg & 7;
    const int xcd = blockIdx.x & 7, idx = blockIdx.x >> 3;
    const int wgid = (xcd < rres ? xcd * (q + 1) : rres * (q + 1) + (xcd - rres) * q) + idx;
    const int rb = wgid % nrb, cb = wgid / nrb;
    const int brow = rb * 256, bcol = cb * 256;

    // staging: per-thread source offset (inverse of read-side swizzle).
    // thread writes LDS (lr=tid>>2, physslot=tid&3) which holds logical slot
    // (tid&3)^(lr&3) of row lr.
    const int srow = tid >> 2;
    const int scol = (tid & 3) ^ (srow & 3);
    const size_t soff = (size_t)srow * H + scol * 16;
    const uint8_t* XA0 = X8 + (size_t)brow * H + soff;
    const uint8_t* XA1 = XA0 + (size_t)128 * H;
    const uint8_t* WB0 = W8 + (size_t)bcol * H + soff;
    const uint8_t* WB1 = WB0 + (size_t)128 * H;

#define STAGE(gbase, kbyte, region) \
    __builtin_amdgcn_global_load_lds((const GLOBAL_AS uint32_t*)((gbase) + (kbyte)), \
                                     (LDS_AS uint32_t*)((region) + wave * 1024), 16, 0, 0)

    f32x16 acc[2][2][2] = {};   // [mh][nh][mi]
    i32x8 a01[2], a23[2], bfr[2];

    // ---- prologue: tile0 {A0,B0,A1,B1}, tile1 {A0,B0,A1}  (7 issues)
    STAGE(XA0, 0, AR(0, 0));
    STAGE(WB0, 0, BR(0, 0));
    STAGE(XA1, 0, AR(0, 1));
    STAGE(WB1, 0, BR(0, 1));
    if (NT > 1) {
        STAGE(XA0, 64, AR(1, 0));
        STAGE(WB0, 64, BR(1, 0));
        STAGE(XA1, 64, AR(1, 1));
        asm volatile("s_waitcnt vmcnt(3)" ::: "memory");
    } else {
        asm volatile("s_waitcnt vmcnt(0)" ::: "memory");
    }
    __builtin_amdgcn_s_barrier();
    a01[0] = frag_read(AR(0, 0), wr * 64 + l31, kb);
    a01[1] = frag_read(AR(0, 0), wr * 64 + 32 + l31, kb);

#pragma unroll 2
    for (int t = 0; t < NT; ++t) {
        const int buf = t & 1;
        const int k1 = (t + 1) * 64, k2 = (t + 2) * 64;

        // ---- phase 0 (mh=0): read b(t), a23(t); MFMA; stage B1(t+1), A0(t+2); W0
        bfr[0] = frag_read(BR(buf, 0), wc * 32 + l31, kb);
        bfr[1] = frag_read(BR(buf, 1), wc * 32 + l31, kb);
        a23[0] = frag_read(AR(buf, 1), wr * 64 + l31, kb);
        a23[1] = frag_read(AR(buf, 1), wr * 64 + 32 + l31, kb);
        __builtin_amdgcn_s_setprio(1);
        MFMA8(a01[0], bfr[0], acc[0][0][0]);
        MFMA8(a01[1], bfr[0], acc[0][0][1]);
        MFMA8(a01[0], bfr[1], acc[0][1][0]);
        MFMA8(a01[1], bfr[1], acc[0][1][1]);
        __builtin_amdgcn_s_setprio(0);
        if (t + 1 < NT) STAGE(WB1, k1, BR(buf ^ 1, 1));
        if (t + 2 < NT) {
            STAGE(XA0, k2, AR(buf, 0));
            asm volatile("s_waitcnt vmcnt(2)" ::: "memory");   // {A0,B0,A1}(t+1) landed
        } else if (t + 1 < NT) {
            asm volatile("s_waitcnt vmcnt(1)" ::: "memory");
        }
        __builtin_amdgcn_s_barrier();

        // ---- phase 1 (mh=1): preread a01(t+1); MFMA; stage B0(t+2), A1(t+2); W1
        if (t + 1 < NT) {
            a01[0] = frag_read(AR(buf ^ 1, 0), wr * 64 + l31, kb);
            a01[1] = frag_read(AR(buf ^ 1, 0), wr * 64 + 32 + l31, kb);
        }
        __builtin_amdgcn_s_setprio(1);
        MFMA8(a23[0], bfr[0], acc[1][0][0]);
        MFMA8(a23[1], bfr[0], acc[1][0][1]);
        MFMA8(a23[0], bfr[1], acc[1][1][0]);
        MFMA8(a23[1], bfr[1], acc[1][1][1]);
        __builtin_amdgcn_s_setprio(0);
        if (t + 2 < NT) {
            STAGE(WB0, k2, BR(buf, 0));
            STAGE(XA1, k2, AR(buf, 1));
            asm volatile("s_waitcnt vmcnt(3)" ::: "memory");   // B1(t+1) landed
        } else if (t + 1 < NT) {
            asm volatile("s_waitcnt vmcnt(0)" ::: "memory");
        }
        __builtin_amdgcn_s_barrier();
    }

    // ---- epilogue: descale, per-row max/sumexp over 256 cols + target pick
    __syncthreads();
    float (*red_m)[4] = (float(*)[4])smem;
    float (*red_s)[4] = (float(*)[4])(smem + 4096);
    int* tgt_l = (int*)(smem + 8192);
    if (tid < 256) {
        long long tt = target[brow + tid];
        if (tt < 0) tt = 0;
        if (tt >= V) tt = (long long)V - 1;
        tgt_l[tid] = (int)tt;
    }
    __syncthreads();

    const float inv = 1.0f / 4096.0f;
    const int c0 = wc * 32 + l31;
#pragma unroll
    for (int mh = 0; mh < 2; ++mh)
#pragma unroll
        for (int mi = 0; mi < 2; ++mi)
#pragma unroll
            for (int j = 0; j < 16; ++j) {
                int rif = (j & 3) + 8 * (j >> 2) + 4 * (lane >> 5);
                int row = mh * 128 + wr * 64 + mi * 32 + rif;
                int tc = tgt_l[row] - bcol;
                float v0 = acc[mh][0][mi][j] * inv;
                float v1 = acc[mh][1][mi][j] * inv;
                if (tc == c0) tgt_logit[brow + row] = v0;
                if (tc == 128 + c0) tgt_logit[brow + row] = v1;
                float mx = fmaxf(v0, v1);
#pragma unroll
                for (int d = 1; d < 32; d <<= 1) mx = fmaxf(mx, __shfl_xor(mx, d));
                float s = __expf(v0 - mx) + __expf(v1 - mx);
#pragma unroll
                for (int d = 1; d < 32; d <<= 1) s += __shfl_xor(s, d);
                if (l31 == 0) { red_m[row][wc] = mx; red_s[row][wc] = s; }
            }
    __syncthreads();
    if (tid < 256) {
        float m0 = red_m[tid][0], m1 = red_m[tid][1];
        float m2 = red_m[tid][2], m3 = red_m[tid][3];
        float M = fmaxf(fmaxf(m0, m1), fmaxf(m2, m3));
        float S = red_s[tid][0] * __expf(m0 - M) + red_s[tid][1] * __expf(m1 - M)
                + red_s[tid][2] * __expf(m2 - M) + red_s[tid][3] * __expf(m3 - M);
        partials[(size_t)cb * BT + brow + tid] = make_float2(M, S);
    }
#undef AR
#undef BR
#undef STAGE
}

// ---------------------------------------------------------------- fp32 fallback (128^2, m97 structure)
__global__ void flce_gemm_f32(const float* __restrict__ X, const float* __restrict__ Wf,
                              const long long* __restrict__ target,
                              float2* __restrict__ partials, float* __restrict__ tgt_logit,
                              int BT, int H, int V, int nrb) {
    __shared__ uint16_t As[128 * 32];
    __shared__ uint16_t Bs[128 * 32];
    __shared__ float red_m[128][2];
    __shared__ float red_s[128][2];
    __shared__ int tgt_l[128];

    const int tid = threadIdx.x;
    const int wave = tid >> 6, lane = tid & 63;
    const int wr = wave >> 1, wc = wave & 1;
    const int l16 = lane & 15, lh = lane >> 4;
    const int bid = blockIdx.x;
    const int rb = bid % nrb, cb = bid / nrb;
    const int brow = rb * 128, bcol = cb * 128;

    if (tid < 128) {
        long long t = target[brow + tid];
        if (t < 0) t = 0;
        if (t >= V) t = (long long)V - 1;
        tgt_l[tid] = (int)t;
    }

    f32x4 acc[4][4] = {};
    for (int k0 = 0; k0 < H; k0 += 32) {
        __syncthreads();
#pragma unroll
        for (int j = 0; j < 4; ++j) {
            int fi = tid + j * 256;
            int row = fi >> 3;
            int kk = (fi & 7) << 2;
            float4 av = *(const float4*)(X + (size_t)(brow + row) * H + k0 + kk);
            float4 bv = *(const float4*)(Wf + (size_t)(bcol + row) * H + k0 + kk);
            u16x4 au, bu;
            au[0] = f2b(av.x); au[1] = f2b(av.y); au[2] = f2b(av.z); au[3] = f2b(av.w);
            bu[0] = f2b(bv.x); bu[1] = f2b(bv.y); bu[2] = f2b(bv.z); bu[3] = f2b(bv.w);
            *(u16x4*)&As[row * 32 + kk] = au;
            *(u16x4*)&Bs[row * 32 + kk] = bu;
        }
        __syncthreads();
        bf16x8 af[4], bf[4];
#pragma unroll
        for (int m = 0; m < 4; ++m)
            af[m] = *(const bf16x8*)&As[(wr * 64 + m * 16 + l16) * 32 + lh * 8];
#pragma unroll
        for (int n = 0; n < 4; ++n)
            bf[n] = *(const bf16x8*)&Bs[(wc * 64 + n * 16 + l16) * 32 + lh * 8];
#pragma unroll
        for (int m = 0; m < 4; ++m)
#pragma unroll
            for (int n = 0; n < 4; ++n)
                acc[m][n] = __builtin_amdgcn_mfma_f32_16x16x32_bf16(af[m], bf[n], acc[m][n], 0, 0, 0);
    }
#pragma unroll
    for (int m = 0; m < 4; ++m) {
#pragma unroll
        for (int r = 0; r < 4; ++r) {
            int rowl = wr * 64 + m * 16 + lh * 4 + r;
            int tc = tgt_l[rowl] - bcol;
            float mx = -INFINITY;
#pragma unroll
            for (int n = 0; n < 4; ++n) {
                float v = acc[m][n][r];
                if (tc == wc * 64 + n * 16 + l16) tgt_logit[brow + rowl] = v;
                mx = fmaxf(mx, v);
            }
#pragma unroll
            for (int d = 1; d < 16; d <<= 1) mx = fmaxf(mx, __shfl_xor(mx, d));
            float s = 0.f;
#pragma unroll
            for (int n = 0; n < 4; ++n) s += __expf(acc[m][n][r] - mx);
#pragma unroll
            for (int d = 1; d < 16; d <<= 1) s += __shfl_xor(s, d);
            if (l16 == 0) { red_m[rowl][wc] = mx; red_s[rowl][wc] = s; }
        }
    }
    __syncthreads();
    if (tid < 128) {
        float m0 = red_m[tid][0], m1 = red_m[tid][1];
        float s0 = red_s[tid][0], s1 = red_s[tid][1];
        float M = fmaxf(m0, m1);
        float S = s0 * __expf(m0 - M) + s1 * __expf(m1 - M);
        partials[(size_t)cb * BT + brow + tid] = make_float2(M, S);
    }
}

// ---------------------------------------------------------------- per-row LSE merge + block sums
__global__ void flce_reduce(const float2* __restrict__ partials,
                            const float* __restrict__ tgt_logit,
                            const long long* __restrict__ target,
                            float2* __restrict__ bsums, int BT, int NCB) {
    int row = blockIdx.x * blockDim.x + threadIdx.x;
    float M = -INFINITY, S = 0.f;
    for (int cbi = 0; cbi < NCB; ++cbi) {
        float2 p = partials[(size_t)cbi * BT + row];
        float Mn = fmaxf(M, p.x);
        S = S * __expf(M - Mn) + p.y * __expf(p.x - Mn);
        M = Mn;
    }
    float lse = M + __logf(S);
    bool valid = (target[row] != -100);
    float nll = valid ? (lse - tgt_logit[row]) : 0.f;
    float cnt = valid ? 1.f : 0.f;
#pragma unroll
    for (int d = 1; d < 64; d <<= 1) { nll += __shfl_xor(nll, d); cnt += __shfl_xor(cnt, d); }
    __shared__ float sm[8][2];
    int w = threadIdx.x >> 6;
    if ((threadIdx.x & 63) == 0) { sm[w][0] = nll; sm[w][1] = cnt; }
    __syncthreads();
    if (threadIdx.x == 0) {
        float sn = 0.f, sc = 0.f;
        int nw = blockDim.x >> 6;
        for (int i = 0; i < nw; ++i) { sn += sm[i][0]; sc += sm[i][1]; }
        bsums[blockIdx.x] = make_float2(sn, sc);
    }
}

__global__ void flce_final(const float2* __restrict__ bsums, int nb, float* __restrict__ out) {
    if (blockIdx.x == 0 && threadIdx.x == 0) {
        float sn = 0.f, sc = 0.f;
        for (int i = 0; i < nb; ++i) { sn += bsums[i].x; sc += bsums[i].y; }
        out[0] = sn / sc;
    }
}

// ---------------------------------------------------------------- launch
extern "C" void kernel_launch(void* const* d_in, const int* in_sizes, int n_in,
                              void* d_out, int out_size, void* d_ws, size_t ws_size,
                              hipStream_t stream) {
    const float* x = (const float*)d_in[0];
    const float* w = (const float*)d_in[1];
    const long long* target = (const long long*)d_in[2];
    float* out = (float*)d_out;

    const int BT = in_sizes[2];
    const int H = in_sizes[0] / BT;
    const int V = in_sizes[1] / H;
    const int nred = BT / 256;

    char* ws = (char*)d_ws;
    size_t szW = (size_t)V * H;            // fp8: 1 B/elem
    size_t szX = (size_t)BT * H;
    const int nrb = BT / 256;              // 16
    const int ncb = V / 256;               // 125
    size_t szPart = (size_t)ncb * BT * sizeof(float2);
    size_t szTgt = (size_t)BT * sizeof(float);
    size_t szB = (size_t)nred * sizeof(float2);

    bool use8 = ws_size >= szW + szX + szPart + szTgt + szB;

    if (use8) {
        uint8_t* W8 = (uint8_t*)ws;
        uint8_t* X8 = (uint8_t*)(ws + szW);
        float2* partials = (float2*)(ws + szW + szX);
        float* tgtlog = (float*)(ws + szW + szX + szPart);
        float2* bsums = (float2*)(ws + szW + szX + szPart + szTgt);

        hipLaunchKernelGGL(cvt8_kernel, dim3(1024), dim3(256), 0, stream,
                           x, (uint2*)X8, (size_t)BT * H / 8);
        hipLaunchKernelGGL(cvt8_kernel, dim3(4096), dim3(256), 0, stream,
                           w, (uint2*)W8, (size_t)V * H / 8);
        hipLaunchKernelGGL(flce_gemm_fp8, dim3(nrb * ncb), dim3(512), 0, stream,
                           X8, W8, target, partials, tgtlog, BT, H, V, nrb);
        hipLaunchKernelGGL(flce_reduce, dim3(BT / 256), dim3(256), 0, stream,
                           partials, tgtlog, target, bsums, BT, ncb);
        hipLaunchKernelGGL(flce_final, dim3(1), dim3(64), 0, stream, bsums, nred, out);
    } else {
        const int nrb1 = BT / 128, ncb1 = V / 128;
        float2* partials = (float2*)ws;
        float* tgtlog = (float*)(ws + (size_t)ncb1 * BT * sizeof(float2));
        float2* bsums = (float2*)(ws + (size_t)ncb1 * BT * sizeof(float2) + szTgt);
        hipLaunchKernelGGL(flce_gemm_f32, dim3(nrb1 * ncb1), dim3(256), 0, stream,
                           x, w, target, partials, tgtlog, BT, H, V, nrb1);
        hipLaunchKernelGGL(flce_reduce, dim3(BT / 256), dim3(256), 0, stream,
                           partials, tgtlog, target, bsums, BT, ncb1);
        hipLaunchKernelGGL(flce_final, dim3(1), dim3(64), 0, stream, bsums, nred, out);
    }
}

// Round 5
// 925.261 us; speedup vs baseline: 1.5398x; 1.0396x over previous
//
#include <hip/hip_runtime.h>
#include <hip/hip_bf16.h>
#include <cstdint>
#include <cstddef>

typedef __attribute__((ext_vector_type(8))) short bf16x8;
typedef __attribute__((ext_vector_type(4))) float f32x4;
typedef __attribute__((ext_vector_type(16))) float f32x16;
typedef __attribute__((ext_vector_type(4))) int i32x4;
typedef __attribute__((ext_vector_type(8))) int i32x8;
typedef __attribute__((ext_vector_type(4))) uint16_t u16x4;
typedef __attribute__((ext_vector_type(8))) uint16_t u16x8;

#define GLOBAL_AS __attribute__((address_space(1)))
#define LDS_AS __attribute__((address_space(3)))

__device__ inline uint16_t f2b(float f) {
    uint32_t x = __float_as_uint(f);
    uint32_t r = (x + 0x7fffu + ((x >> 16) & 1u)) >> 16;
    return (uint16_t)r;
}

// ---------------------------------------------------------------- convert fp32 -> fp8 e4m3 (x64 prescale)
__global__ void cvt8_kernel(const float* __restrict__ in, uint2* __restrict__ out, size_t n8) {
    size_t stride = (size_t)gridDim.x * blockDim.x;
    for (size_t i = (size_t)blockIdx.x * blockDim.x + threadIdx.x; i < n8; i += stride) {
        const float4* p = (const float4*)(in + i * 8);
        float4 a = p[0], b = p[1];
        int w0 = __builtin_amdgcn_cvt_pk_fp8_f32(a.x * 64.f, a.y * 64.f, 0, false);
        w0 = __builtin_amdgcn_cvt_pk_fp8_f32(a.z * 64.f, a.w * 64.f, w0, true);
        int w1 = __builtin_amdgcn_cvt_pk_fp8_f32(b.x * 64.f, b.y * 64.f, 0, false);
        w1 = __builtin_amdgcn_cvt_pk_fp8_f32(b.z * 64.f, b.w * 64.f, w1, true);
        out[i] = make_uint2((unsigned)w0, (unsigned)w1);
    }
}

// ---------------------------------------------------------------- fp8 MX GEMM + fused LSE partials
// 256x256 tile, BK=64, 8 waves (2x4), 32x32x64 f8f6f4 MFMA, identity HW scales,
// epilogue descales by 1/4096 (inputs prescaled by 64 each).
// LDS regions: 128 rows x 64 B. Bank-group of a 16B slot = 4*(row&1) + slot.
// R5 swizzle: physslot = kslot ^ ((row>>1)&3)  ->  group bijective in (row mod 8):
// 32 lanes/read spread 4 per group (minimum) — conflict-free. (R4's row&3 variant
// collided: group used only 4/8 values -> 1.5e8 conflict cycles.)

#define SC8 0x7F7F7F7F

__device__ __forceinline__ i32x8 frag_read(const char* region, int lr, int kb) {
    const int swz = ((lr >> 1) & 3) << 4;
    const char* rp = region + lr * 64;
    i32x4 lo = *(const i32x4*)(rp + (kb ^ swz));
    i32x4 hi = *(const i32x4*)(rp + ((kb + 16) ^ swz));
    i32x8 f;
    f[0] = lo[0]; f[1] = lo[1]; f[2] = lo[2]; f[3] = lo[3];
    f[4] = hi[0]; f[5] = hi[1]; f[6] = hi[2]; f[7] = hi[3];
    return f;
}

#define MFMA8(aa, bb, cc) cc = __builtin_amdgcn_mfma_scale_f32_32x32x64_f8f6f4( \
        aa, bb, cc, 0, 0, 0, SC8, 0, SC8)

__global__ __launch_bounds__(512, 2)
void flce_gemm_fp8(const uint8_t* __restrict__ X8, const uint8_t* __restrict__ W8,
                   const long long* __restrict__ target,
                   float2* __restrict__ partials, float* __restrict__ tgt_logit,
                   int BT, int H, int V, int nrb) {
    __shared__ __align__(16) char smem[65536];
    char* Ab = smem;            // 4 regions x 8 KB: (buf*2+mh)
    char* Bb = smem + 32768;
#define AR(bf, hf) (Ab + ((bf) * 2 + (hf)) * 8192)
#define BR(bf, hf) (Bb + ((bf) * 2 + (hf)) * 8192)

    const int tid = threadIdx.x;
    const int lane = tid & 63, wave = tid >> 6;
    const int wr = wave >> 2, wc = wave & 3;
    const int l31 = lane & 31;
    const int kb = (lane >> 5) * 32;      // fragment k-byte base
    const int NT = H / 64;

    // bijective XCD swizzle (m204), rb-fastest
    const int nwg = gridDim.x;
    const int q = nwg >> 3, rres = nwg & 7;
    const int xcd = blockIdx.x & 7, idx = blockIdx.x >> 3;
    const int wgid = (xcd < rres ? xcd * (q + 1) : rres * (q + 1) + (xcd - rres) * q) + idx;
    const int rb = wgid % nrb, cb = wgid / nrb;
    const int brow = rb * 256, bcol = cb * 256;

    // staging: per-thread source offset (inverse of read-side swizzle).
    // thread tid writes LDS physical (row=tid>>2, physslot=tid&3), which the
    // reader interprets as logical kslot = physslot ^ ((row>>1)&3).
    const int srow = tid >> 2;
    const int scol = (tid & 3) ^ ((srow >> 1) & 3);
    const size_t soff = (size_t)srow * H + scol * 16;
    const uint8_t* XA0 = X8 + (size_t)brow * H + soff;
    const uint8_t* XA1 = XA0 + (size_t)128 * H;
    const uint8_t* WB0 = W8 + (size_t)bcol * H + soff;
    const uint8_t* WB1 = WB0 + (size_t)128 * H;

#define STAGE(gbase, kbyte, region) \
    __builtin_amdgcn_global_load_lds((const GLOBAL_AS uint32_t*)((gbase) + (kbyte)), \
                                     (LDS_AS uint32_t*)((region) + wave * 1024), 16, 0, 0)

    f32x16 acc[2][2][2] = {};   // [mh][nh][mi]
    i32x8 a01[2], a23[2], bfr[2];

    // ---- prologue: tile0 {A0,B0,A1,B1}, tile1 {A0,B0,A1}  (7 issues)
    STAGE(XA0, 0, AR(0, 0));
    STAGE(WB0, 0, BR(0, 0));
    STAGE(XA1, 0, AR(0, 1));
    STAGE(WB1, 0, BR(0, 1));
    if (NT > 1) {
        STAGE(XA0, 64, AR(1, 0));
        STAGE(WB0, 64, BR(1, 0));
        STAGE(XA1, 64, AR(1, 1));
        asm volatile("s_waitcnt vmcnt(3)" ::: "memory");
    } else {
        asm volatile("s_waitcnt vmcnt(0)" ::: "memory");
    }
    __builtin_amdgcn_s_barrier();
    a01[0] = frag_read(AR(0, 0), wr * 64 + l31, kb);
    a01[1] = frag_read(AR(0, 0), wr * 64 + 32 + l31, kb);

#pragma unroll 2
    for (int t = 0; t < NT; ++t) {
        const int buf = t & 1;
        const int k1 = (t + 1) * 64, k2 = (t + 2) * 64;

        // ---- phase 0 (mh=0): read b(t), a23(t); MFMA; stage B1(t+1), A0(t+2); W0
        bfr[0] = frag_read(BR(buf, 0), wc * 32 + l31, kb);
        bfr[1] = frag_read(BR(buf, 1), wc * 32 + l31, kb);
        a23[0] = frag_read(AR(buf, 1), wr * 64 + l31, kb);
        a23[1] = frag_read(AR(buf, 1), wr * 64 + 32 + l31, kb);
        __builtin_amdgcn_s_setprio(1);
        MFMA8(a01[0], bfr[0], acc[0][0][0]);
        MFMA8(a01[1], bfr[0], acc[0][0][1]);
        MFMA8(a01[0], bfr[1], acc[0][1][0]);
        MFMA8(a01[1], bfr[1], acc[0][1][1]);
        __builtin_amdgcn_s_setprio(0);
        if (t + 1 < NT) STAGE(WB1, k1, BR(buf ^ 1, 1));
        if (t + 2 < NT) {
            STAGE(XA0, k2, AR(buf, 0));
            asm volatile("s_waitcnt vmcnt(2)" ::: "memory");   // {A0,B0,A1}(t+1) landed
        } else if (t + 1 < NT) {
            asm volatile("s_waitcnt vmcnt(1)" ::: "memory");
        }
        __builtin_amdgcn_s_barrier();

        // ---- phase 1 (mh=1): preread a01(t+1); MFMA; stage B0(t+2), A1(t+2); W1
        if (t + 1 < NT) {
            a01[0] = frag_read(AR(buf ^ 1, 0), wr * 64 + l31, kb);
            a01[1] = frag_read(AR(buf ^ 1, 0), wr * 64 + 32 + l31, kb);
        }
        __builtin_amdgcn_s_setprio(1);
        MFMA8(a23[0], bfr[0], acc[1][0][0]);
        MFMA8(a23[1], bfr[0], acc[1][0][1]);
        MFMA8(a23[0], bfr[1], acc[1][1][0]);
        MFMA8(a23[1], bfr[1], acc[1][1][1]);
        __builtin_amdgcn_s_setprio(0);
        if (t + 2 < NT) {
            STAGE(WB0, k2, BR(buf, 0));
            STAGE(XA1, k2, AR(buf, 1));
            asm volatile("s_waitcnt vmcnt(3)" ::: "memory");   // B1(t+1) landed
        } else if (t + 1 < NT) {
            asm volatile("s_waitcnt vmcnt(0)" ::: "memory");
        }
        __builtin_amdgcn_s_barrier();
    }

    // ---- epilogue: descale, per-row max/sumexp over 256 cols + target pick
    __syncthreads();
    float (*red_m)[4] = (float(*)[4])smem;
    float (*red_s)[4] = (float(*)[4])(smem + 4096);
    int* tgt_l = (int*)(smem + 8192);
    if (tid < 256) {
        long long tt = target[brow + tid];
        if (tt < 0) tt = 0;
        if (tt >= V) tt = (long long)V - 1;
        tgt_l[tid] = (int)tt;
    }
    __syncthreads();

    const float inv = 1.0f / 4096.0f;
    const int c0 = wc * 32 + l31;
#pragma unroll
    for (int mh = 0; mh < 2; ++mh)
#pragma unroll
        for (int mi = 0; mi < 2; ++mi)
#pragma unroll
            for (int j = 0; j < 16; ++j) {
                int rif = (j & 3) + 8 * (j >> 2) + 4 * (lane >> 5);
                int row = mh * 128 + wr * 64 + mi * 32 + rif;
                int tc = tgt_l[row] - bcol;
                float v0 = acc[mh][0][mi][j] * inv;
                float v1 = acc[mh][1][mi][j] * inv;
                if (tc == c0) tgt_logit[brow + row] = v0;
                if (tc == 128 + c0) tgt_logit[brow + row] = v1;
                float mx = fmaxf(v0, v1);
#pragma unroll
                for (int d = 1; d < 32; d <<= 1) mx = fmaxf(mx, __shfl_xor(mx, d));
                float s = __expf(v0 - mx) + __expf(v1 - mx);
#pragma unroll
                for (int d = 1; d < 32; d <<= 1) s += __shfl_xor(s, d);
                if (l31 == 0) { red_m[row][wc] = mx; red_s[row][wc] = s; }
            }
    __syncthreads();
    if (tid < 256) {
        float m0 = red_m[tid][0], m1 = red_m[tid][1];
        float m2 = red_m[tid][2], m3 = red_m[tid][3];
        float M = fmaxf(fmaxf(m0, m1), fmaxf(m2, m3));
        float S = red_s[tid][0] * __expf(m0 - M) + red_s[tid][1] * __expf(m1 - M)
                + red_s[tid][2] * __expf(m2 - M) + red_s[tid][3] * __expf(m3 - M);
        partials[(size_t)cb * BT + brow + tid] = make_float2(M, S);
    }
#undef AR
#undef BR
#undef STAGE
}

// ---------------------------------------------------------------- fp32 fallback (128^2, m97 structure)
__global__ void flce_gemm_f32(const float* __restrict__ X, const float* __restrict__ Wf,
                              const long long* __restrict__ target,
                              float2* __restrict__ partials, float* __restrict__ tgt_logit,
                              int BT, int H, int V, int nrb) {
    __shared__ uint16_t As[128 * 32];
    __shared__ uint16_t Bs[128 * 32];
    __shared__ float red_m[128][2];
    __shared__ float red_s[128][2];
    __shared__ int tgt_l[128];

    const int tid = threadIdx.x;
    const int wave = tid >> 6, lane = tid & 63;
    const int wr = wave >> 1, wc = wave & 1;
    const int l16 = lane & 15, lh = lane >> 4;
    const int bid = blockIdx.x;
    const int rb = bid % nrb, cb = bid / nrb;
    const int brow = rb * 128, bcol = cb * 128;

    if (tid < 128) {
        long long t = target[brow + tid];
        if (t < 0) t = 0;
        if (t >= V) t = (long long)V - 1;
        tgt_l[tid] = (int)t;
    }

    f32x4 acc[4][4] = {};
    for (int k0 = 0; k0 < H; k0 += 32) {
        __syncthreads();
#pragma unroll
        for (int j = 0; j < 4; ++j) {
            int fi = tid + j * 256;
            int row = fi >> 3;
            int kk = (fi & 7) << 2;
            float4 av = *(const float4*)(X + (size_t)(brow + row) * H + k0 + kk);
            float4 bv = *(const float4*)(Wf + (size_t)(bcol + row) * H + k0 + kk);
            u16x4 au, bu;
            au[0] = f2b(av.x); au[1] = f2b(av.y); au[2] = f2b(av.z); au[3] = f2b(av.w);
            bu[0] = f2b(bv.x); bu[1] = f2b(bv.y); bu[2] = f2b(bv.z); bu[3] = f2b(bv.w);
            *(u16x4*)&As[row * 32 + kk] = au;
            *(u16x4*)&Bs[row * 32 + kk] = bu;
        }
        __syncthreads();
        bf16x8 af[4], bf[4];
#pragma unroll
        for (int m = 0; m < 4; ++m)
            af[m] = *(const bf16x8*)&As[(wr * 64 + m * 16 + l16) * 32 + lh * 8];
#pragma unroll
        for (int n = 0; n < 4; ++n)
            bf[n] = *(const bf16x8*)&Bs[(wc * 64 + n * 16 + l16) * 32 + lh * 8];
#pragma unroll
        for (int m = 0; m < 4; ++m)
#pragma unroll
            for (int n = 0; n < 4; ++n)
                acc[m][n] = __builtin_amdgcn_mfma_f32_16x16x32_bf16(af[m], bf[n], acc[m][n], 0, 0, 0);
    }
#pragma unroll
    for (int m = 0; m < 4; ++m) {
#pragma unroll
        for (int r = 0; r < 4; ++r) {
            int rowl = wr * 64 + m * 16 + lh * 4 + r;
            int tc = tgt_l[rowl] - bcol;
            float mx = -INFINITY;
#pragma unroll
            for (int n = 0; n < 4; ++n) {
                float v = acc[m][n][r];
                if (tc == wc * 64 + n * 16 + l16) tgt_logit[brow + rowl] = v;
                mx = fmaxf(mx, v);
            }
#pragma unroll
            for (int d = 1; d < 16; d <<= 1) mx = fmaxf(mx, __shfl_xor(mx, d));
            float s = 0.f;
#pragma unroll
            for (int n = 0; n < 4; ++n) s += __expf(acc[m][n][r] - mx);
#pragma unroll
            for (int d = 1; d < 16; d <<= 1) s += __shfl_xor(s, d);
            if (l16 == 0) { red_m[rowl][wc] = mx; red_s[rowl][wc] = s; }
        }
    }
    __syncthreads();
    if (tid < 128) {
        float m0 = red_m[tid][0], m1 = red_m[tid][1];
        float s0 = red_s[tid][0], s1 = red_s[tid][1];
        float M = fmaxf(m0, m1);
        float S = s0 * __expf(m0 - M) + s1 * __expf(m1 - M);
        partials[(size_t)cb * BT + brow + tid] = make_float2(M, S);
    }
}

// ---------------------------------------------------------------- per-row LSE merge + block sums
__global__ void flce_reduce(const float2* __restrict__ partials,
                            const float* __restrict__ tgt_logit,
                            const long long* __restrict__ target,
                            float2* __restrict__ bsums, int BT, int NCB) {
    int row = blockIdx.x * blockDim.x + threadIdx.x;
    float M = -INFINITY, S = 0.f;
    for (int cbi = 0; cbi < NCB; ++cbi) {
        float2 p = partials[(size_t)cbi * BT + row];
        float Mn = fmaxf(M, p.x);
        S = S * __expf(M - Mn) + p.y * __expf(p.x - Mn);
        M = Mn;
    }
    float lse = M + __logf(S);
    bool valid = (target[row] != -100);
    float nll = valid ? (lse - tgt_logit[row]) : 0.f;
    float cnt = valid ? 1.f : 0.f;
#pragma unroll
    for (int d = 1; d < 64; d <<= 1) { nll += __shfl_xor(nll, d); cnt += __shfl_xor(cnt, d); }
    __shared__ float sm[8][2];
    int w = threadIdx.x >> 6;
    if ((threadIdx.x & 63) == 0) { sm[w][0] = nll; sm[w][1] = cnt; }
    __syncthreads();
    if (threadIdx.x == 0) {
        float sn = 0.f, sc = 0.f;
        int nw = blockDim.x >> 6;
        for (int i = 0; i < nw; ++i) { sn += sm[i][0]; sc += sm[i][1]; }
        bsums[blockIdx.x] = make_float2(sn, sc);
    }
}

__global__ void flce_final(const float2* __restrict__ bsums, int nb, float* __restrict__ out) {
    if (blockIdx.x == 0 && threadIdx.x == 0) {
        float sn = 0.f, sc = 0.f;
        for (int i = 0; i < nb; ++i) { sn += bsums[i].x; sc += bsums[i].y; }
        out[0] = sn / sc;
    }
}

// ---------------------------------------------------------------- launch
extern "C" void kernel_launch(void* const* d_in, const int* in_sizes, int n_in,
                              void* d_out, int out_size, void* d_ws, size_t ws_size,
                              hipStream_t stream) {
    const float* x = (const float*)d_in[0];
    const float* w = (const float*)d_in[1];
    const long long* target = (const long long*)d_in[2];
    float* out = (float*)d_out;

    const int BT = in_sizes[2];
    const int H = in_sizes[0] / BT;
    const int V = in_sizes[1] / H;
    const int nred = BT / 256;

    char* ws = (char*)d_ws;
    size_t szW = (size_t)V * H;            // fp8: 1 B/elem
    size_t szX = (size_t)BT * H;
    const int nrb = BT / 256;              // 16
    const int ncb = V / 256;               // 125
    size_t szPart = (size_t)ncb * BT * sizeof(float2);
    size_t szTgt = (size_t)BT * sizeof(float);
    size_t szB = (size_t)nred * sizeof(float2);

    bool use8 = ws_size >= szW + szX + szPart + szTgt + szB;

    if (use8) {
        uint8_t* W8 = (uint8_t*)ws;
        uint8_t* X8 = (uint8_t*)(ws + szW);
        float2* partials = (float2*)(ws + szW + szX);
        float* tgtlog = (float*)(ws + szW + szX + szPart);
        float2* bsums = (float2*)(ws + szW + szX + szPart + szTgt);

        hipLaunchKernelGGL(cvt8_kernel, dim3(1024), dim3(256), 0, stream,
                           x, (uint2*)X8, (size_t)BT * H / 8);
        hipLaunchKernelGGL(cvt8_kernel, dim3(4096), dim3(256), 0, stream,
                           w, (uint2*)W8, (size_t)V * H / 8);
        hipLaunchKernelGGL(flce_gemm_fp8, dim3(nrb * ncb), dim3(512), 0, stream,
                           X8, W8, target, partials, tgtlog, BT, H, V, nrb);
        hipLaunchKernelGGL(flce_reduce, dim3(BT / 256), dim3(256), 0, stream,
                           partials, tgtlog, target, bsums, BT, ncb);
        hipLaunchKernelGGL(flce_final, dim3(1), dim3(64), 0, stream, bsums, nred, out);
    } else {
        const int nrb1 = BT / 128, ncb1 = V / 128;
        float2* partials = (float2*)ws;
        float* tgtlog = (float*)(ws + (size_t)ncb1 * BT * sizeof(float2));
        float2* bsums = (float2*)(ws + (size_t)ncb1 * BT * sizeof(float2) + szTgt);
        hipLaunchKernelGGL(flce_gemm_f32, dim3(nrb1 * ncb1), dim3(256), 0, stream,
                           x, w, target, partials, tgtlog, BT, H, V, nrb1);
        hipLaunchKernelGGL(flce_reduce, dim3(BT / 256), dim3(256), 0, stream,
                           partials, tgtlog, target, bsums, BT, ncb1);
        hipLaunchKernelGGL(flce_final, dim3(1), dim3(64), 0, stream, bsums, nred, out);
    }
}